// Round 1
// baseline (249.007 us; speedup 1.0000x reference)
//
#include <hip/hip_runtime.h>

#define BB 2
#define LL 2048
#define EE 1024
#define HH 16
#define HDD 64
// M = BB*LL = 4096 rows for both GEMMs

typedef __bf16 bf16x8 __attribute__((ext_vector_type(8)));
typedef float f32x4 __attribute__((ext_vector_type(4)));

__device__ __forceinline__ unsigned short f2bf(float f) {
  unsigned int x = __float_as_uint(f);
  return (unsigned short)((x + 0x7FFFu + ((x >> 16) & 1u)) >> 16);  // RNE
}

// ---------------- cast fp32 -> bf16 for GEMM inputs (4 segments) -------------
__global__ __launch_bounds__(256) void cast_kernel(
    const float* __restrict__ q, const float* __restrict__ pe,
    const float* __restrict__ wq, const float* __restrict__ wp,
    unsigned short* __restrict__ q16, unsigned short* __restrict__ pe16,
    unsigned short* __restrict__ wq16, unsigned short* __restrict__ wp16) {
  const int NQ4 = BB * LL * EE / 4;   // 1048576
  const int NW4 = EE * EE / 4;        // 262144
  int i = blockIdx.x * 256 + threadIdx.x;
  const float* src; unsigned short* dst; int off;
  if (i < NQ4)                { src = q;  dst = q16;  off = i; }
  else if (i < 2 * NQ4)       { src = pe; dst = pe16; off = i - NQ4; }
  else if (i < 2 * NQ4 + NW4) { src = wq; dst = wq16; off = i - 2 * NQ4; }
  else                        { src = wp; dst = wp16; off = i - 2 * NQ4 - NW4; }
  float4 v = ((const float4*)src)[off];
  ushort4 u;
  u.x = f2bf(v.x); u.y = f2bf(v.y); u.z = f2bf(v.z); u.w = f2bf(v.w);
  ((ushort4*)dst)[off] = u;
}

// ---------------- column sums of key/value over L ----------------------------
// grid (EE/256, 32, BB), block 256; 64 rows per y-slice; atomic accumulate.
__global__ __launch_bounds__(256) void sumkv_kernel(
    const float* __restrict__ key, const float* __restrict__ value,
    float* __restrict__ keysum, float* __restrict__ valsum) {
  int e = blockIdx.x * 256 + threadIdx.x;
  int b = blockIdx.z;
  int l0 = blockIdx.y * 64;
  size_t base = ((size_t)b * LL + l0) * EE + e;
  float ak = 0.f, av = 0.f;
  for (int i = 0; i < 64; i++) {
    ak += key[base + (size_t)i * EE];
    av += value[base + (size_t)i * EE];
  }
  atomicAdd(&keysum[b * EE + e], ak);
  atomicAdd(&valsum[b * EE + e], av);
}

// ---------------- project summed key/value: sum @ W.T + L*bias ---------------
// grid (BB*EE/4, 1, 2), block 256 (4 waves, one output per wave)
__global__ __launch_bounds__(256) void proj_kernel(
    const float* __restrict__ keysum, const float* __restrict__ valsum,
    const float* __restrict__ Wk, const float* __restrict__ bk,
    const float* __restrict__ Wv, const float* __restrict__ bv,
    float* __restrict__ Kproj, float* __restrict__ Vproj) {
  int wv = threadIdx.x >> 6, lane = threadIdx.x & 63;
  int idx = blockIdx.x * 4 + wv;          // [0, BB*EE)
  int b = idx >> 10, ep = idx & (EE - 1);
  const float* sum  = blockIdx.z ? valsum : keysum;
  const float* W    = blockIdx.z ? Wv : Wk;
  const float* bias = blockIdx.z ? bv : bk;
  float* outp       = blockIdx.z ? Vproj : Kproj;
  float acc = 0.f;
  for (int k = lane; k < EE; k += 64) acc += sum[b * EE + k] * W[ep * EE + k];
  for (int off = 32; off; off >>= 1) acc += __shfl_down(acc, off, 64);
  if (lane == 0) outp[b * EE + ep] = acc + (float)LL * bias[ep];
}

// ---------------- W2[b,h,e] = sum_d Vproj[b,h*64+d] * Wo[e, h*64+d] ----------
// grid (BB*HH*EE/4), block 256 (one wave per output)
__global__ __launch_bounds__(256) void w2_kernel(
    const float* __restrict__ Vproj, const float* __restrict__ Wo,
    float* __restrict__ W2) {
  int wv = threadIdx.x >> 6, lane = threadIdx.x & 63;
  int idx = blockIdx.x * 4 + wv;          // [0, 32768)
  int e = idx & (EE - 1);
  int h = (idx >> 10) & (HH - 1);
  int b = idx >> 14;
  float acc = Vproj[b * EE + h * HDD + lane] * Wo[(size_t)e * EE + h * HDD + lane];
  for (int off = 32; off; off >>= 1) acc += __shfl_down(acc, off, 64);
  if (lane == 0) W2[((size_t)b * HH + h) * EE + e] = acc;
}

// ---------------- bf16 MFMA GEMM: Out[M,N] = X[M,K] @ W[N,K]^T (+bias) -------
// 128x128 tile, BK=32, 4 waves, each wave 64x64 via 4x4 MFMAs of 16x16x32.
// grid (N/128=8, M/128=32, 2): z=0 -> q projection (+bq), z=1 -> r projection.
__global__ __launch_bounds__(256) void gemm_kernel(
    const unsigned short* __restrict__ q16, const unsigned short* __restrict__ wq16,
    const float* __restrict__ bq, float* __restrict__ qout,
    const unsigned short* __restrict__ pe16, const unsigned short* __restrict__ wp16,
    float* __restrict__ rout) {
  const int K = EE, N = EE;
  const unsigned short* X; const unsigned short* W; const float* bias; float* Out;
  if (blockIdx.z == 0) { X = q16;  W = wq16; bias = bq;      Out = qout; }
  else                 { X = pe16; W = wp16; bias = nullptr; Out = rout; }

  __shared__ __align__(16) unsigned short As[128 * 32];
  __shared__ __align__(16) unsigned short Bs[128 * 32];

  const int tid = threadIdx.x;
  const int lane = tid & 63;
  const int wv = tid >> 6;
  const int wr = wv >> 1, wc = wv & 1;
  const int n0 = blockIdx.x * 128;
  const int m0 = blockIdx.y * 128;

  const int srow = tid >> 2;           // 0..63
  const int skc = (tid & 3) * 8;       // 0,8,16,24

  f32x4 acc[4][4];
#pragma unroll
  for (int i = 0; i < 4; i++)
#pragma unroll
    for (int j = 0; j < 4; j++) acc[i][j] = (f32x4)0.0f;

  const int arow = wr * 64 + (lane & 15);
  const int brow = wc * 64 + (lane & 15);
  const int koff = (lane >> 4) * 8;

  for (int kk = 0; kk < K; kk += 32) {
    *(uint4*)&As[srow * 32 + skc]        = *(const uint4*)&X[(size_t)(m0 + srow) * K + kk + skc];
    *(uint4*)&As[(srow + 64) * 32 + skc] = *(const uint4*)&X[(size_t)(m0 + srow + 64) * K + kk + skc];
    *(uint4*)&Bs[srow * 32 + skc]        = *(const uint4*)&W[(size_t)(n0 + srow) * K + kk + skc];
    *(uint4*)&Bs[(srow + 64) * 32 + skc] = *(const uint4*)&W[(size_t)(n0 + srow + 64) * K + kk + skc];
    __syncthreads();
    bf16x8 af[4], bf[4];
#pragma unroll
    for (int i = 0; i < 4; i++) af[i] = *(const bf16x8*)&As[(arow + i * 16) * 32 + koff];
#pragma unroll
    for (int j = 0; j < 4; j++) bf[j] = *(const bf16x8*)&Bs[(brow + j * 16) * 32 + koff];
#pragma unroll
    for (int i = 0; i < 4; i++)
#pragma unroll
      for (int j = 0; j < 4; j++)
        acc[i][j] = __builtin_amdgcn_mfma_f32_16x16x32_bf16(af[i], bf[j], acc[i][j], 0, 0, 0);
    __syncthreads();
  }

  // epilogue: C/D layout col=lane&15, row=(lane>>4)*4+g  [verified m89/m91]
  const int rbase = m0 + wr * 64 + (lane >> 4) * 4;
  const int cbase = n0 + wc * 64 + (lane & 15);
#pragma unroll
  for (int i = 0; i < 4; i++) {
#pragma unroll
    for (int j = 0; j < 4; j++) {
      int col = cbase + j * 16;
      float badd = bias ? bias[col] : 0.f;
#pragma unroll
      for (int g = 0; g < 4; g++) {
        int row = rbase + i * 16 + g;
        Out[(size_t)row * N + col] = acc[i][j][g] + badd;
      }
    }
  }
}

// ---------------- prefix scan of r over sequence: stage 1 (chunk sums) -------
// grid (EE/256, 32, BB), block 256; chunk = 64 rows
__global__ __launch_bounds__(256) void scan1_kernel(
    const float* __restrict__ r, float* __restrict__ chunksum) {
  int e = blockIdx.x * 256 + threadIdx.x;
  int ch = blockIdx.y, b = blockIdx.z;
  size_t base = ((size_t)b * LL + ch * 64) * EE + e;
  float a = 0.f;
  for (int i = 0; i < 64; i++) a += r[base + (size_t)i * EE];
  chunksum[((size_t)b * 32 + ch) * EE + e] = a;
}

// ---------------- prefix scan stage 2: write P[b, m, e], m = 0..L ------------
__global__ __launch_bounds__(256) void scan2_kernel(
    const float* __restrict__ r, const float* __restrict__ chunksum,
    float* __restrict__ P) {
  int e = blockIdx.x * 256 + threadIdx.x;
  int ch = blockIdx.y, b = blockIdx.z;
  float pre = 0.f;
  for (int c = 0; c < ch; c++) pre += chunksum[((size_t)b * 32 + c) * EE + e];
  size_t Pbase = (size_t)b * (LL + 1) * EE;
  if (ch == 0) P[Pbase + e] = 0.f;
  size_t rbase = ((size_t)b * LL + ch * 64) * EE + e;
  float run = pre;
  for (int i = 0; i < 64; i++) {
    run += r[rbase + (size_t)i * EE];
    P[Pbase + (size_t)(ch * 64 + i + 1) * EE + e] = run;
  }
}

// ---------------- score row-sums S[b,h,p] ------------------------------------
// one wave per (b,p); lane = d within head; loop over 16 heads.
// S*32 = (q+U).Kproj + (q+V).(P[L]-P[L-p-1]) + (q_{p+1}+V).P[L-p-2]
__global__ __launch_bounds__(256) void score_kernel(
    const float* __restrict__ q, const float* __restrict__ P,
    const float* __restrict__ Kproj, const float* __restrict__ U,
    const float* __restrict__ V, float* __restrict__ S) {
  int wv = threadIdx.x >> 6, lane = threadIdx.x & 63;
  int g = blockIdx.x * 4 + wv;            // [0, BB*LL)
  int b = g >> 11, p = g & (LL - 1);
  size_t qrow = (size_t)(b * LL + p) * EE;
  size_t Pbase = (size_t)b * (LL + 1) * EE;
  size_t prowL = Pbase + (size_t)LL * EE;
  size_t prowA = Pbase + (size_t)(LL - p - 1) * EE;
  bool hasB = (p < LL - 1);
  size_t prowB = hasB ? (Pbase + (size_t)(LL - p - 2) * EE) : Pbase;
  for (int h = 0; h < HH; h++) {
    int d = h * HDD + lane;
    float qd = q[qrow + d];
    float q2 = hasB ? q[qrow + EE + d] : 0.f;
    float kp = Kproj[b * EE + d];
    float pl = P[prowL + d];
    float pa = P[prowA + d];
    float pb = hasB ? P[prowB + d] : 0.f;
    float Uh = U[d], Vh = V[d];
    float t = (qd + Uh) * kp + (qd + Vh) * (pl - pa) + (q2 + Vh) * pb;
    for (int off = 32; off; off >>= 1) t += __shfl_down(t, off, 64);
    if (lane == 0) S[((size_t)b * HH + h) * LL + p] = t * (1.f / 32.f);
  }
}

// ---------------- output: out[b,p,:] = sum_h S[b,h,p]*W2[b,h,:] + bo ---------
// grid BB*LL blocks, block 256
__global__ __launch_bounds__(256) void out_kernel(
    const float* __restrict__ S, const float* __restrict__ W2,
    const float* __restrict__ bo, float* __restrict__ out) {
  int row = blockIdx.x;                   // [0, BB*LL)
  int b = row >> 11, p = row & (LL - 1);
  __shared__ float sh[HH];
  if (threadIdx.x < HH) sh[threadIdx.x] = S[((size_t)b * HH + threadIdx.x) * LL + p];
  __syncthreads();
  for (int e = threadIdx.x; e < EE; e += 256) {
    float acc = bo[e];
#pragma unroll
    for (int h = 0; h < HH; h++) acc += sh[h] * W2[((size_t)b * HH + h) * EE + e];
    out[(size_t)row * EE + e] = acc;
  }
}

extern "C" void kernel_launch(void* const* d_in, const int* in_sizes, int n_in,
                              void* d_out, int out_size, void* d_ws, size_t ws_size,
                              hipStream_t stream) {
  const float* query = (const float*)d_in[0];
  const float* key   = (const float*)d_in[1];
  const float* value = (const float*)d_in[2];
  const float* pos   = (const float*)d_in[3];
  const float* Wq = (const float*)d_in[4];
  const float* bq = (const float*)d_in[5];
  const float* Wk = (const float*)d_in[6];
  const float* bk = (const float*)d_in[7];
  const float* Wv = (const float*)d_in[8];
  const float* bv = (const float*)d_in[9];
  const float* Wp = (const float*)d_in[10];
  const float* Wo = (const float*)d_in[11];
  const float* bo = (const float*)d_in[12];
  const float* U  = (const float*)d_in[13];
  const float* V  = (const float*)d_in[14];
  float* out = (float*)d_out;

  char* ws = (char*)d_ws;
  size_t o = 0;
  auto take = [&](size_t bytes) -> char* {
    char* p = ws + o;
    o += (bytes + 255) & ~(size_t)255;
    return p;
  };
  float* keysum = (float*)take(BB * EE * 4);
  float* valsum = (float*)take(BB * EE * 4);
  float* Kproj  = (float*)take(BB * EE * 4);
  float* Vproj  = (float*)take(BB * EE * 4);
  float* W2     = (float*)take((size_t)BB * HH * EE * 4);
  float* S      = (float*)take((size_t)BB * HH * LL * 4);
  float* chunks = (float*)take((size_t)BB * 32 * EE * 4);
  float* qbuf   = (float*)take((size_t)BB * LL * EE * 4);
  float* rbuf   = (float*)take((size_t)BB * LL * EE * 4);
  float* Pbuf   = (float*)take((size_t)BB * (LL + 1) * EE * 4);
  unsigned short* q16  = (unsigned short*)take((size_t)BB * LL * EE * 2);
  unsigned short* pe16 = (unsigned short*)take((size_t)BB * LL * EE * 2);
  unsigned short* wq16 = (unsigned short*)take((size_t)EE * EE * 2);
  unsigned short* wp16 = (unsigned short*)take((size_t)EE * EE * 2);

  // zero the atomic accumulators (keysum, valsum are adjacent)
  hipMemsetAsync(keysum, 0, (size_t)2 * BB * EE * 4, stream);

  cast_kernel<<<10240, 256, 0, stream>>>(query, pos, Wq, Wp, q16, pe16, wq16, wp16);
  sumkv_kernel<<<dim3(EE / 256, 32, BB), 256, 0, stream>>>(key, value, keysum, valsum);
  proj_kernel<<<dim3(BB * EE / 4, 1, 2), 256, 0, stream>>>(keysum, valsum, Wk, bk, Wv, bv, Kproj, Vproj);
  w2_kernel<<<dim3(BB * HH * EE / 4), 256, 0, stream>>>(Vproj, Wo, W2);
  gemm_kernel<<<dim3(EE / 128, BB * LL / 128, 2), 256, 0, stream>>>(q16, wq16, bq, qbuf, pe16, wp16, rbuf);
  scan1_kernel<<<dim3(EE / 256, 32, BB), 256, 0, stream>>>(rbuf, chunks);
  scan2_kernel<<<dim3(EE / 256, 32, BB), 256, 0, stream>>>(rbuf, chunks, Pbuf);
  score_kernel<<<dim3(BB * LL / 4), 256, 0, stream>>>(qbuf, Pbuf, Kproj, U, V, S);
  out_kernel<<<dim3(BB * LL), 256, 0, stream>>>(S, W2, bo, out);
}